// Round 8
// baseline (91.181 us; speedup 1.0000x reference)
//
#include <hip/hip_runtime.h>
#include <stdint.h>

typedef __attribute__((ext_vector_type(8))) short short8;
typedef __attribute__((ext_vector_type(4))) short s16x4;
typedef __attribute__((ext_vector_type(4))) float f32x4;

#define D_K 128
#define N_KV 8192
#define NT 128          /* 64-row q tiles */

// ---------- helpers ----------
__device__ __forceinline__ unsigned short f2bf(float x) {
  unsigned int u = __float_as_uint(x);
  u += 0x7FFFu + ((u >> 16) & 1u);  // RNE
  return (unsigned short)(u >> 16);
}
__device__ __forceinline__ unsigned int pk2(float lo, float hi) {
  return (unsigned int)f2bf(lo) | ((unsigned int)f2bf(hi) << 16);
}
__device__ __forceinline__ unsigned int cvtpk(float lo, float hi) {
  unsigned int r;
  asm("v_cvt_pk_bf16_f32 %0, %1, %2" : "=v"(r) : "v"(lo), "v"(hi));
  return r;
}
__device__ __forceinline__ f32x4 mfma16(s16x4 a, s16x4 b, f32x4 c) {
  asm("v_mfma_f32_16x16x16_bf16 %0, %1, %2, %0" : "+v"(c) : "v"(a), "v"(b));
  return c;
}
__device__ __forceinline__ void gload16(const void* g, void* l) {
  __builtin_amdgcn_global_load_lds(
      (const __attribute__((address_space(1))) unsigned int*)g,
      (__attribute__((address_space(3))) unsigned int*)l, 16, 0, 0);
}
__device__ __host__ __forceinline__ int nunits(int t) {
  int n = 2 * t + 2;
  return n > 252 ? 252 : n;
}

// ---------- fused prep: Q-cast, K-cast, V-transpose in one launch ----------
__global__ void prep_kernel(const float* __restrict__ Q,
                            const float* __restrict__ K,
                            const float* __restrict__ V,
                            unsigned short* __restrict__ Qb,
                            unsigned short* __restrict__ Kb,
                            unsigned short* __restrict__ Vtb) {
  __shared__ unsigned short tile[64][65];
  const int b = blockIdx.x;
  const int tid = threadIdx.x;
  if (b < 1024) {
    const float scale = (b < 512) ? 0.12751742941349835f : 1.0f;  // (1/sqrt(128))*log2(e)
    const float* src = (b < 512) ? Q : K;
    unsigned short* dst = (b < 512) ? Qb : Kb;
    const int i = (b & 511) * 256 + tid;
    const float4* s = (const float4*)src;
    float4 a = s[2 * i], c4 = s[2 * i + 1];
    uint4 o;
    o.x = pk2(a.x * scale, a.y * scale);
    o.y = pk2(a.z * scale, a.w * scale);
    o.z = pk2(c4.x * scale, c4.y * scale);
    o.w = pk2(c4.z * scale, c4.w * scale);
    *(uint4*)(dst + (size_t)i * 8) = o;
  } else {
    const int bb = b - 1024;
    const int kv0 = (bb >> 1) << 6, dk0 = (bb & 1) << 6;
    const int r = tid >> 2;
    const int c0 = (tid & 3) << 4;
#pragma unroll
    for (int j = 0; j < 4; ++j) {
      float4 v = *(const float4*)(V + (size_t)(kv0 + r) * D_K + dk0 + c0 + 4 * j);
      tile[r][c0 + 4 * j + 0] = f2bf(v.x);
      tile[r][c0 + 4 * j + 1] = f2bf(v.y);
      tile[r][c0 + 4 * j + 2] = f2bf(v.z);
      tile[r][c0 + 4 * j + 3] = f2bf(v.w);
    }
    __syncthreads();
    __align__(16) unsigned short tmp[16];
#pragma unroll
    for (int j = 0; j < 16; ++j) tmp[j] = tile[c0 + j][r];
    unsigned short* o = Vtb + (size_t)(dk0 + r) * N_KV + kv0 + c0;
    *(uint4*)(o) = *(uint4*)(tmp);
    *(uint4*)(o + 8) = *(uint4*)(tmp + 8);
  }
}

// ---------- main: BQ=64, 2-buffer 1-barrier loop, 4 blocks/CU ----------
// QK^T swapped -> S^T; PV transposed (O^T = V^T P^T, K=16): P stays in
// registers (cvt_pk only), per-lane rescale, coalesced f32x4 epilogue.
__global__ __launch_bounds__(256, 4) void attn_kernel(
    const unsigned short* __restrict__ Qb,   // [8192][128] bf16 pre-scaled
    const unsigned short* __restrict__ Kb,   // [8192][128] bf16
    const unsigned short* __restrict__ Vtb,  // [128][8192] bf16
    float* __restrict__ Opart,               // [slots][64][128]
    float2* __restrict__ MLpart,             // [slots][64]
    int U) {
  // ---- block -> (tile t, chunk s); big tiles first ----
  int rem = blockIdx.x, t = NT - 1;
  for (;; --t) {
    int nb = (nunits(t) + U - 1) / U;
    if (rem < nb) break;
    rem -= nb;
  }
  const int s = rem;
  const int q0 = t << 6;
  const int n = nunits(t);
  const int u0 = s * U;
  const int u1 = min(u0 + U, n);
  const int slot = blockIdx.x;
  const int tid = threadIdx.x;
  const int lane = tid & 63;
  const int w = tid >> 6;
  const int c = lane & 15;
  const int g = lane >> 4;
  const int qw = q0 + (w << 4);

  __shared__ __align__(16) char lds[32768];  // 2 x (K 8KB + Vt 8KB)

  // Q fragments (B operand of QK^T): lane(c,g) = Q[qw+c][32kc+8g..+7]
  short8 qf[4];
  {
    const char* qrow = (const char*)(Qb + (size_t)(qw + c) * D_K);
#pragma unroll
    for (int kc = 0; kc < 4; ++kc)
      qf[kc] = *(const short8*)(qrow + kc * 64 + g * 16);
  }

  // accT[dblk][r] = O[q=qw+c][d=16dblk+4g+r]  (transposed C-layout)
  f32x4 accT[8] = {};
  float m2 = -3e38f, lsum = 0.f;
  const int swp = (c & 3) << 4;
  const int vo0 = (g << 3) ^ swp;
  const int vo1 = (32 + (g << 3)) ^ swp;

  // staging constants (pre-swizzled source, linear LDS dest)
  int kcst[2], vcst[2], ldk[2], ldv[2];
#pragma unroll
  for (int ii = 0; ii < 2; ++ii) {
    const int ck = 2 * w + ii;
    const int rowK = (ck << 2) + (lane >> 4);
    kcst[ii] = rowK * 256 + (((lane & 15) << 4) ^ ((rowK & 7) << 4));
    ldk[ii] = ck << 10;
    const int rowV = (ck << 4) + (lane >> 2);
    vcst[ii] = rowV * 16384 + (((lane & 3) << 4) ^ ((rowV & 3) << 4));
    ldv[ii] = 8192 + (ck << 10);
  }
  auto stage = [&](int u, int b) {
    char* base = lds + b * 16384;
    const int koff = (u << 5) * 256;
    const int voff = (u << 5) * 2;
#pragma unroll
    for (int ii = 0; ii < 2; ++ii) {
      gload16((const char*)Kb + koff + kcst[ii], base + ldk[ii]);
      gload16((const char*)Vtb + voff + vcst[ii], base + ldv[ii]);
    }
  };

  stage(u0, 0);                  // 4 loads outstanding
  int cb = 0;
  for (int u = u0; u < u1; ++u) {
    // barrier: guarantees buffer cb^1 (unit u-1) fully consumed by all waves
    __builtin_amdgcn_s_barrier();
    asm volatile("" ::: "memory");
    if (u + 1 < u1) {
      stage(u + 1, cb ^ 1);                            // 8 outstanding
      asm volatile("s_waitcnt vmcnt(4)" ::: "memory"); // u's 4 done
    } else {
      asm volatile("s_waitcnt vmcnt(0)" ::: "memory");
    }
    const int kv0 = u << 5;
    char* const Kl = lds + cb * 16384;
    char* const Vl = Kl + 8192;

    if (kv0 <= qw + 15) {
      // ---- QK^T (swapped): st[tt][r] = S[q=c][kv=16tt+4g+r] ----
      f32x4 st[2] = {};
      __builtin_amdgcn_s_setprio(1);
#pragma unroll
      for (int tt = 0; tt < 2; ++tt) {
        const int krow = (tt << 4) + c;
        const char* kbase = Kl + krow * 256;
        const int swk = (krow & 7) << 4;
#pragma unroll
        for (int kc = 0; kc < 4; ++kc) {
          short8 kf = *(const short8*)(kbase + ((kc * 64 + g * 16) ^ swk));
          st[tt] = __builtin_amdgcn_mfma_f32_16x16x32_bf16(kf, qf[kc], st[tt], 0, 0, 0);
        }
      }
      __builtin_amdgcn_s_setprio(0);
      // ---- causal mask ----
#pragma unroll
      for (int tt = 0; tt < 2; ++tt) {
        if (kv0 + (tt << 4) + 15 > qw) {
          const int kvb = kv0 + (tt << 4) + (g << 2);
#pragma unroll
          for (int r = 0; r < 4; ++r)
            if (kvb + r > qw + c) st[tt][r] = -__builtin_inff();
        }
      }
      // ---- online softmax (exp2 domain), per-lane q=c, defer-max ----
      float mx = fmaxf(fmaxf(fmaxf(st[0][0], st[0][1]), fmaxf(st[0][2], st[0][3])),
                       fmaxf(fmaxf(st[1][0], st[1][1]), fmaxf(st[1][2], st[1][3])));
      mx = fmaxf(mx, __shfl_xor(mx, 16));
      mx = fmaxf(mx, __shfl_xor(mx, 32));
      if (!__all(mx <= m2 + 8.0f)) {             // T13
        const float m2new = fmaxf(m2, mx);
        const float alpha = exp2f(m2 - m2new);   // per-lane (acc col q=c)
        lsum *= alpha;
#pragma unroll
        for (int d = 0; d < 8; ++d)
#pragma unroll
          for (int r = 0; r < 4; ++r) accT[d][r] *= alpha;
        m2 = m2new;
      }
      float p[8], psum = 0.f;
#pragma unroll
      for (int tt = 0; tt < 2; ++tt)
#pragma unroll
        for (int r = 0; r < 4; ++r) {
          const float v = exp2f(st[tt][r] - m2);
          p[(tt << 2) + r] = v;
          psum += v;
        }
      psum += __shfl_xor(psum, 16);
      psum += __shfl_xor(psum, 32);
      lsum += psum;
      // ---- P fragments in place ----
      union PB { unsigned int u2[2]; s16x4 s4; };
      PB pb0, pb1;
      pb0.u2[0] = cvtpk(p[0], p[1]);
      pb0.u2[1] = cvtpk(p[2], p[3]);
      pb1.u2[0] = cvtpk(p[4], p[5]);
      pb1.u2[1] = cvtpk(p[6], p[7]);
      // ---- PV (transposed, K=16), 8 independent acc chains per phase ----
      __builtin_amdgcn_s_setprio(1);
      {
        s16x4 va[8];
#pragma unroll
        for (int d = 0; d < 8; ++d)
          va[d] = *(const s16x4*)(Vl + (d << 10) + c * 64 + vo0);
#pragma unroll
        for (int d = 0; d < 8; ++d) accT[d] = mfma16(va[d], pb0.s4, accT[d]);
#pragma unroll
        for (int d = 0; d < 8; ++d)
          va[d] = *(const s16x4*)(Vl + (d << 10) + c * 64 + vo1);
#pragma unroll
        for (int d = 0; d < 8; ++d) accT[d] = mfma16(va[d], pb1.s4, accT[d]);
      }
      __builtin_amdgcn_s_setprio(0);
    }
    cb ^= 1;
  }

  // ---- epilogue: partial O (coalesced f32x4) and (m,l) ----
  float* op = Opart + (size_t)slot * 8192 + (size_t)((w << 4) + c) * 128 + (g << 2);
#pragma unroll
  for (int d = 0; d < 8; ++d)
    *(f32x4*)(op + (d << 4)) = accT[d];
  if (lane < 16)
    MLpart[slot * 64 + (w << 4) + lane] = make_float2(m2, lsum);
}

// ---------- combine variable-count partials ----------
__global__ void combine_kernel(const float* __restrict__ Opart,
                               const float2* __restrict__ MLpart,
                               float* __restrict__ Out, int U) {
  const int gidx = blockIdx.x * 256 + threadIdx.x;  // 8192*32
  const int q = gidx >> 5;
  const int cb = (gidx & 31) << 2;
  const int t = q >> 6, rl = q & 63;
  const int ns = (nunits(t) + U - 1) / U;
  int base = 0;
  for (int tt = NT - 1; tt > t; --tt) base += (nunits(tt) + U - 1) / U;

  float M = -3e38f;
  for (int s2 = 0; s2 < ns; ++s2)
    M = fmaxf(M, MLpart[(base + s2) * 64 + rl].x);
  float nx = 0, ny = 0, nz = 0, nw = 0, den = 0;
  for (int s2 = 0; s2 < ns; ++s2) {
    const float2 ml = MLpart[(base + s2) * 64 + rl];
    if (ml.x > -1e37f) {
      const float wg = exp2f(ml.x - M);
      den += ml.y * wg;
      const float4 o = *(const float4*)(Opart + (size_t)(base + s2) * 8192 + rl * 128 + cb);
      nx += wg * o.x; ny += wg * o.y; nz += wg * o.z; nw += wg * o.w;
    }
  }
  const float inv = 1.f / den;
  float4 r; r.x = nx * inv; r.y = ny * inv; r.z = nz * inv; r.w = nw * inv;
  *(float4*)(Out + (size_t)q * 128 + cb) = r;
}

extern "C" void kernel_launch(void* const* d_in, const int* in_sizes, int n_in,
                              void* d_out, int out_size, void* d_ws, size_t ws_size,
                              hipStream_t stream) {
  (void)in_sizes; (void)n_in; (void)out_size;
  const float* Q = (const float*)d_in[0];
  const float* K = (const float*)d_in[1];
  const float* V = (const float*)d_in[2];
  float* out = (float*)d_out;
  char* ws = (char*)d_ws;

  // pick U so slots <= 1020 (one residency pass at 4 blocks/CU) and ws fits
  int U = 4;
  long slots = 0;
  for (;;) {
    slots = 0;
    for (int t = 0; t < NT; ++t) slots += (nunits(t) + U - 1) / U;
    size_t need = (size_t)(8u << 20) + (size_t)slots * 64 * 128 * 4;
    if ((slots <= 1020 && need <= ws_size) || U >= 252) break;
    ++U;
  }

  unsigned short* Qb  = (unsigned short*)(ws);
  unsigned short* Kb  = (unsigned short*)(ws + (1u << 21));
  unsigned short* Vtb = (unsigned short*)(ws + (2u << 21));
  float2* MLp = (float2*)(ws + (3u << 21));
  float*  Op  = (float*)(ws + (8u << 20));

  prep_kernel<<<1280, 256, 0, stream>>>(Q, K, V, Qb, Kb, Vtb);
  attn_kernel<<<(int)slots, 256, 0, stream>>>(Qb, Kb, Vtb, Op, MLp, U);
  combine_kernel<<<1024, 256, 0, stream>>>(Op, MLp, out, U);
}

// Round 9
// 74.247 us; speedup vs baseline: 1.2281x; 1.2281x over previous
//
#include <hip/hip_runtime.h>
#include <stdint.h>

typedef __attribute__((ext_vector_type(8))) short short8;
typedef __attribute__((ext_vector_type(4))) short s16x4;
typedef __attribute__((ext_vector_type(4))) float f32x4;

#define D_K 128
#define N_KV 8192
#define NT2 64          /* 128-row q tiles */

// ---------- helpers ----------
__device__ __forceinline__ unsigned short f2bf(float x) {
  unsigned int u = __float_as_uint(x);
  u += 0x7FFFu + ((u >> 16) & 1u);  // RNE
  return (unsigned short)(u >> 16);
}
__device__ __forceinline__ unsigned int pk2(float lo, float hi) {
  return (unsigned int)f2bf(lo) | ((unsigned int)f2bf(hi) << 16);
}
__device__ __forceinline__ unsigned int cvtpk(float lo, float hi) {
  unsigned int r;
  asm("v_cvt_pk_bf16_f32 %0, %1, %2" : "=v"(r) : "v"(lo), "v"(hi));
  return r;
}
__device__ __forceinline__ f32x4 mfma16(s16x4 a, s16x4 b, f32x4 c) {
  asm("v_mfma_f32_16x16x16_bf16 %0, %1, %2, %0" : "+v"(c) : "v"(a), "v"(b));
  return c;
}
__device__ __forceinline__ void gload16(const void* g, void* l) {
  __builtin_amdgcn_global_load_lds(
      (const __attribute__((address_space(1))) unsigned int*)g,
      (__attribute__((address_space(3))) unsigned int*)l, 16, 0, 0);
}
__device__ __host__ __forceinline__ int nunits64(int t) {
  int n = 4 * t + 4;
  return n > 252 ? 252 : n;
}

// ---------- fused prep: Q-cast, K-cast, V-transpose in one launch ----------
__global__ void prep_kernel(const float* __restrict__ Q,
                            const float* __restrict__ K,
                            const float* __restrict__ V,
                            unsigned short* __restrict__ Qb,
                            unsigned short* __restrict__ Kb,
                            unsigned short* __restrict__ Vtb) {
  __shared__ unsigned short tile[64][65];
  const int b = blockIdx.x;
  const int tid = threadIdx.x;
  if (b < 1024) {
    const float scale = (b < 512) ? 0.12751742941349835f : 1.0f;  // (1/sqrt(128))*log2(e)
    const float* src = (b < 512) ? Q : K;
    unsigned short* dst = (b < 512) ? Qb : Kb;
    const int i = (b & 511) * 256 + tid;
    const float4* s = (const float4*)src;
    float4 a = s[2 * i], c4 = s[2 * i + 1];
    uint4 o;
    o.x = pk2(a.x * scale, a.y * scale);
    o.y = pk2(a.z * scale, a.w * scale);
    o.z = pk2(c4.x * scale, c4.y * scale);
    o.w = pk2(c4.z * scale, c4.w * scale);
    *(uint4*)(dst + (size_t)i * 8) = o;
  } else {
    const int bb = b - 1024;
    const int kv0 = (bb >> 1) << 6, dk0 = (bb & 1) << 6;
    const int r = tid >> 2;
    const int c0 = (tid & 3) << 4;
#pragma unroll
    for (int j = 0; j < 4; ++j) {
      float4 v = *(const float4*)(V + (size_t)(kv0 + r) * D_K + dk0 + c0 + 4 * j);
      tile[r][c0 + 4 * j + 0] = f2bf(v.x);
      tile[r][c0 + 4 * j + 1] = f2bf(v.y);
      tile[r][c0 + 4 * j + 2] = f2bf(v.z);
      tile[r][c0 + 4 * j + 3] = f2bf(v.w);
    }
    __syncthreads();
    __align__(16) unsigned short tmp[16];
#pragma unroll
    for (int j = 0; j < 16; ++j) tmp[j] = tile[c0 + j][r];
    unsigned short* o = Vtb + (size_t)(dk0 + r) * N_KV + kv0 + c0;
    *(uint4*)(o) = *(uint4*)(tmp);
    *(uint4*)(o + 8) = *(uint4*)(tmp + 8);
  }
}

// ---------- main: BQ=128, 2 strips/wave, 3-buffer depth-2 pipeline ----------
// Softmax: NO cross-lane ops in the common path — local max + __all gate
// (T13), per-lane partial lsum reduced once in the epilogue.
__global__ __launch_bounds__(256, 3) void attn_kernel(
    const unsigned short* __restrict__ Qb,   // [8192][128] bf16 pre-scaled
    const unsigned short* __restrict__ Kb,   // [8192][128] bf16
    const unsigned short* __restrict__ Vtb,  // [128][8192] bf16
    float* __restrict__ Opart,               // [slots][128][128]
    float2* __restrict__ MLpart,             // [slots][128]
    int U) {
  // ---- block -> (tile t, chunk s); big tiles first ----
  int rem = blockIdx.x, t = NT2 - 1;
  for (;; --t) {
    int nb = (nunits64(t) + U - 1) / U;
    if (rem < nb) break;
    rem -= nb;
  }
  const int s = rem;
  const int q0 = t << 7;
  const int n = nunits64(t);
  const int u0 = s * U;
  const int u1 = min(u0 + U, n);
  const int slot = blockIdx.x;
  const int tid = threadIdx.x;
  const int lane = tid & 63;
  const int w = tid >> 6;
  const int c = lane & 15;
  const int g = lane >> 4;
  const int qw = q0 + (w << 5);            // wave rows qw..qw+31

  __shared__ __align__(16) char lds[49152];  // 3 x (K 8KB + Vt 8KB)

  // Q fragments, 2 strips x 4 k-chunks: lane(c,g) = Q[qws+c][32kc+8g..+7]
  short8 qf[2][4];
#pragma unroll
  for (int s2 = 0; s2 < 2; ++s2) {
    const char* qrow = (const char*)(Qb + (size_t)(qw + (s2 << 4) + c) * D_K);
#pragma unroll
    for (int kc = 0; kc < 4; ++kc)
      qf[s2][kc] = *(const short8*)(qrow + kc * 64 + g * 16);
  }

  // accT[s2][dblk][r] = O[q=qws+c][d=16dblk+4g+r]
  f32x4 accT[2][8] = {};
  float m2[2] = {-3e38f, -3e38f}, lsum[2] = {0.f, 0.f};
  const int swp = (c & 3) << 4;
  const int vo0 = (g << 3) ^ swp;
  const int vo1 = (32 + (g << 3)) ^ swp;

  // staging constants (pre-swizzled source, linear LDS dest)
  int kcst[2], vcst[2], ldk[2], ldv[2];
#pragma unroll
  for (int ii = 0; ii < 2; ++ii) {
    const int ck = 2 * w + ii;
    const int rowK = (ck << 2) + (lane >> 4);
    kcst[ii] = rowK * 256 + (((lane & 15) << 4) ^ ((rowK & 7) << 4));
    ldk[ii] = ck << 10;
    const int rowV = (ck << 4) + (lane >> 2);
    vcst[ii] = rowV * 16384 + (((lane & 3) << 4) ^ ((rowV & 3) << 4));
    ldv[ii] = 8192 + (ck << 10);
  }
  auto stage = [&](int u, int b) {
    char* base = lds + b * 16384;
    const int koff = (u << 5) * 256;
    const int voff = (u << 5) * 2;
#pragma unroll
    for (int ii = 0; ii < 2; ++ii) {
      gload16((const char*)Kb + koff + kcst[ii], base + ldk[ii]);
      gload16((const char*)Vtb + voff + vcst[ii], base + ldv[ii]);
    }
  };

  stage(u0, 0);
  if (u0 + 1 < u1) stage(u0 + 1, 1);
  int cb = 0;
  for (int u = u0; u < u1; ++u) {
    if (u + 1 < u1) asm volatile("s_waitcnt vmcnt(4)" ::: "memory");
    else            asm volatile("s_waitcnt vmcnt(0)" ::: "memory");
    __builtin_amdgcn_s_barrier();
    asm volatile("" ::: "memory");
    if (u + 2 < u1) {
      int nb2 = cb + 2; if (nb2 >= 3) nb2 -= 3;
      stage(u + 2, nb2);
    }
    const int kv0 = u << 5;
    char* const Kl = lds + cb * 16384;
    char* const Vl = Kl + 8192;

    if (kv0 <= qw + 31) {                  // wave has live rows in this unit
      // ---- QK^T (swapped): st[s2][tt][r] = S[q=qws+c][kv=16tt+4g+r] ----
      f32x4 st[2][2] = {};
      __builtin_amdgcn_s_setprio(1);
#pragma unroll
      for (int tt = 0; tt < 2; ++tt) {
        const int krow = (tt << 4) + c;
        const char* kbase = Kl + krow * 256;
        const int swk = (krow & 7) << 4;
#pragma unroll
        for (int kc = 0; kc < 4; ++kc) {
          short8 kf = *(const short8*)(kbase + ((kc * 64 + g * 16) ^ swk));
          st[0][tt] = __builtin_amdgcn_mfma_f32_16x16x32_bf16(kf, qf[0][kc], st[0][tt], 0, 0, 0);
          st[1][tt] = __builtin_amdgcn_mfma_f32_16x16x32_bf16(kf, qf[1][kc], st[1][tt], 0, 0, 0);
        }
      }
      __builtin_amdgcn_s_setprio(0);
      // ---- mask + softmax per strip: no cross-lane in common path ----
      union PB { unsigned int u2[2]; s16x4 s4; };
      PB pb[2][2];
#pragma unroll
      for (int s2 = 0; s2 < 2; ++s2) {
        const int qws = qw + (s2 << 4);
#pragma unroll
        for (int tt = 0; tt < 2; ++tt) {
          if (kv0 + (tt << 4) + 15 > qws) {
            const int kvb = kv0 + (tt << 4) + (g << 2);
#pragma unroll
            for (int r = 0; r < 4; ++r)
              if (kvb + r > qws + c) st[s2][tt][r] = -__builtin_inff();
          }
        }
        // per-lane local max (7 fmax, no shfl)
        float mx = fmaxf(fmaxf(fmaxf(st[s2][0][0], st[s2][0][1]), fmaxf(st[s2][0][2], st[s2][0][3])),
                         fmaxf(fmaxf(st[s2][1][0], st[s2][1][1]), fmaxf(st[s2][1][2], st[s2][1][3])));
        if (!__all(mx <= m2[s2] + 8.0f)) {       // rare: cross-lane + rescale
          float mxr = fmaxf(mx, __shfl_xor(mx, 16));
          mxr = fmaxf(mxr, __shfl_xor(mxr, 32));
          const float m2new = fmaxf(m2[s2], mxr);
          const float alpha = exp2f(m2[s2] - m2new);  // per-lane (acc col q=c)
          lsum[s2] *= alpha;
#pragma unroll
          for (int d = 0; d < 8; ++d)
#pragma unroll
            for (int r = 0; r < 4; ++r) accT[s2][d][r] *= alpha;
          m2[s2] = m2new;
        }
        float p[8];
#pragma unroll
        for (int tt = 0; tt < 2; ++tt)
#pragma unroll
          for (int r = 0; r < 4; ++r) {
            const float v = exp2f(st[s2][tt][r] - m2[s2]);
            p[(tt << 2) + r] = v;
            lsum[s2] += v;                       // per-lane partial
          }
        pb[s2][0].u2[0] = cvtpk(p[0], p[1]);
        pb[s2][0].u2[1] = cvtpk(p[2], p[3]);
        pb[s2][1].u2[0] = cvtpk(p[4], p[5]);
        pb[s2][1].u2[1] = cvtpk(p[6], p[7]);
      }
      // ---- PV (transposed, K=16); V-frags shared across strips ----
      __builtin_amdgcn_s_setprio(1);
      {
        s16x4 va[8];
#pragma unroll
        for (int d = 0; d < 8; ++d)
          va[d] = *(const s16x4*)(Vl + (d << 10) + c * 64 + vo0);
#pragma unroll
        for (int d = 0; d < 8; ++d) accT[0][d] = mfma16(va[d], pb[0][0].s4, accT[0][d]);
#pragma unroll
        for (int d = 0; d < 8; ++d) accT[1][d] = mfma16(va[d], pb[1][0].s4, accT[1][d]);
#pragma unroll
        for (int d = 0; d < 8; ++d)
          va[d] = *(const s16x4*)(Vl + (d << 10) + c * 64 + vo1);
#pragma unroll
        for (int d = 0; d < 8; ++d) accT[0][d] = mfma16(va[d], pb[0][1].s4, accT[0][d]);
#pragma unroll
        for (int d = 0; d < 8; ++d) accT[1][d] = mfma16(va[d], pb[1][1].s4, accT[1][d]);
      }
      __builtin_amdgcn_s_setprio(0);
    }
    if (++cb == 3) cb = 0;
  }

  // ---- epilogue: reduce lsum once, write partial O and (m,l) ----
#pragma unroll
  for (int s2 = 0; s2 < 2; ++s2) {
    float lr = lsum[s2];
    lr += __shfl_xor(lr, 16);
    lr += __shfl_xor(lr, 32);
    float* op = Opart + (size_t)slot * 16384 +
                (size_t)((w << 5) + (s2 << 4) + c) * 128 + (g << 2);
#pragma unroll
    for (int d = 0; d < 8; ++d)
      *(f32x4*)(op + (d << 4)) = accT[s2][d];
    if (lane < 16)
      MLpart[slot * 128 + (w << 5) + (s2 << 4) + lane] = make_float2(m2[s2], lr);
  }
}

// ---------- combine variable-count partials ----------
__global__ void combine_kernel(const float* __restrict__ Opart,
                               const float2* __restrict__ MLpart,
                               float* __restrict__ Out, int U) {
  const int gidx = blockIdx.x * 256 + threadIdx.x;  // 8192*32
  const int q = gidx >> 5;
  const int cb = (gidx & 31) << 2;
  const int t = q >> 7, rl = q & 127;
  const int ns = (nunits64(t) + U - 1) / U;
  int base = 0;
  for (int tt = NT2 - 1; tt > t; --tt) base += (nunits64(tt) + U - 1) / U;

  float M = -3e38f;
  for (int s2 = 0; s2 < ns; ++s2)
    M = fmaxf(M, MLpart[(base + s2) * 128 + rl].x);
  float nx = 0, ny = 0, nz = 0, nw = 0, den = 0;
  for (int s2 = 0; s2 < ns; ++s2) {
    const float2 ml = MLpart[(base + s2) * 128 + rl];
    if (ml.x > -1e37f) {
      const float wg = exp2f(ml.x - M);
      den += ml.y * wg;
      const float4 o = *(const float4*)(Opart + (size_t)(base + s2) * 16384 + rl * 128 + cb);
      nx += wg * o.x; ny += wg * o.y; nz += wg * o.z; nw += wg * o.w;
    }
  }
  const float inv = 1.f / den;
  float4 r; r.x = nx * inv; r.y = ny * inv; r.z = nz * inv; r.w = nw * inv;
  *(float4*)(Out + (size_t)q * 128 + cb) = r;
}

extern "C" void kernel_launch(void* const* d_in, const int* in_sizes, int n_in,
                              void* d_out, int out_size, void* d_ws, size_t ws_size,
                              hipStream_t stream) {
  (void)in_sizes; (void)n_in; (void)out_size;
  const float* Q = (const float*)d_in[0];
  const float* K = (const float*)d_in[1];
  const float* V = (const float*)d_in[2];
  float* out = (float*)d_out;
  char* ws = (char*)d_ws;

  // pick U so slots <= 768 (one residency pass at 3 blocks/CU) and ws fits
  int U = 4;
  long slots = 0;
  for (;;) {
    slots = 0;
    for (int t = 0; t < NT2; ++t) slots += (nunits64(t) + U - 1) / U;
    size_t need = (size_t)(8u << 20) + (size_t)slots * 128 * 128 * 4;
    if ((slots <= 768 && need <= ws_size) || U >= 252) break;
    ++U;
  }

  unsigned short* Qb  = (unsigned short*)(ws);
  unsigned short* Kb  = (unsigned short*)(ws + (1u << 21));
  unsigned short* Vtb = (unsigned short*)(ws + (2u << 21));
  float2* MLp = (float2*)(ws + (3u << 21));
  float*  Op  = (float*)(ws + (8u << 20));

  prep_kernel<<<1280, 256, 0, stream>>>(Q, K, V, Qb, Kb, Vtb);
  attn_kernel<<<(int)slots, 256, 0, stream>>>(Qb, Kb, Vtb, Op, MLp, U);
  combine_kernel<<<1024, 256, 0, stream>>>(Op, MLp, out, U);
}